// Round 5
// baseline (1421.070 us; speedup 1.0000x reference)
//
#include <hip/hip_runtime.h>

#define IN_C   16
#define OUT_C  16
#define COEF_M 11
#define PLANE  16384   // 128*128
#define WSIZE  3328    // IN_C*OUT_C*COEF_M + 2*IN_C*OUT_C
#define I0     2816    // IN_C*OUT_C*COEF_M
#define I1     3072    // I0 + IN_C*OUT_C

#define REP 3          // DIAGNOSTIC: 3 idempotent passes so the kan dispatch
                       // rises above the ~270us harness fills in rocprof top-5.
                       // kan_per_pass = dispatch_dur/3, or (dur_us - 414.6)/3.

// v6: max-TLP restructure.
//   thread = (1 pixel, 1 input channel): no acc[] array; o-results go to LDS
//   as produced -> tiny register state -> 64-VGPR cap without spilling.
//   block  = 16 px x 16 i = 256 thr; grid = 32768/16 = 2048 blocks
//          -> 8 blocks/CU, 32 waves/CU (hardware max, 4x v1's TLP).
//   LDS    = 16*16*17*4 = 17408 B -> 8 blocks/CU fits (139 KB < 160 KB).
// Theory: kan is memory-latency-bound at ~700ns loaded latency with only
// ~8KB in flight per CU (8 waves x ~4 outstanding x 256B). 32 waves with the
// same ~4-deep batching gives ~32KB/CU in flight -> BW-limited regime.
__global__ __launch_bounds__(256, 8) void kan_kernel(
    const float* __restrict__ x, const float* __restrict__ w,
    float* __restrict__ out)
{
    const int tid = threadIdx.x;
    const int px  = tid & 15;        // pixel within tile
    const int i   = tid >> 4;        // input channel owned by this thread
    const int pixel = blockIdx.x * 16 + px;
    const int b  = pixel >> 14;      // PLANE = 2^14; tiles never straddle b
    const int hw = pixel & (PLANE - 1);

    const float* wb = w + (size_t)b * WSIZE * PLANE + hw;
    const float* xb = x + (size_t)b * IN_C * PLANE + hw;

    // LDS: [i][px][o + pad]. Write addr = (i*16+px)*17+o = (lane + 64g)*17+o
    // -> 17*lane mod 32 bijective -> conflict-free writes. Reduce reads <=2-way.
    __shared__ float red[16 * 16 * 17];
    const int wrow = (i * 16 + px) * 17;

    for (int rep = 0; rep < REP; ++rep) {
        // block load-LICM across passes: loads must repeat each rep
        asm volatile("" ::: "memory");

        const float xi = xb[(size_t)i * PLANE];

        // Cox-de Boor, order K=3, uniform knots t_j = -1.75 + 0.25*j
        float bp[14];
        #pragma unroll
        for (int j = 0; j < 14; ++j) {
            const float tj = -1.75f + 0.25f * j;
            bp[j] = (xi >= tj && xi < tj + 0.25f) ? 1.0f : 0.0f;
        }
        #pragma unroll
        for (int p = 1; p <= 3; ++p) {
            const float inv = 1.0f / (0.25f * (float)p);
            #pragma unroll
            for (int j = 0; j < 14 - p; ++j) {
                const float tj  = -1.75f + 0.25f * j;
                const float tp1 = tj + 0.25f * (float)(p + 1);
                bp[j] = (xi - tj) * inv * bp[j] + (tp1 - xi) * inv * bp[j + 1];
            }
        }

        const float sx = xi / (1.0f + __expf(-xi));   // silu

        const float* ci = wb + (size_t)(i * (OUT_C * COEF_M)) * PLANE;
        const float* ui = wb + (size_t)(I0 + i * OUT_C) * PLANE;
        const float* ri = wb + (size_t)(I1 + i * OUT_C) * PLANE;

        #pragma unroll
        for (int o = 0; o < OUT_C; ++o) {
            const float* c = ci + (size_t)(o * COEF_M) * PLANE;
            float sp = 0.0f;
            #pragma unroll
            for (int m = 0; m < COEF_M; ++m)
                sp += c[(size_t)m * PLANE] * bp[m];
            red[wrow + o] = ui[(size_t)o * PLANE] * sp + ri[(size_t)o * PLANE] * sx;
        }
        __syncthreads();

        // store phase: thread = (px, o): o = tid>>4 (same lanes-per-px layout)
        const int o = tid >> 4;
        float s = 0.0f;
        #pragma unroll
        for (int ii = 0; ii < 16; ++ii)
            s += red[(ii * 16 + px) * 17 + o];
        out[(size_t)b * (OUT_C * PLANE) + (size_t)o * PLANE + hw] = s;

        __syncthreads();   // red[] reused next pass
    }
}

extern "C" void kernel_launch(void* const* d_in, const int* in_sizes, int n_in,
                              void* d_out, int out_size, void* d_ws, size_t ws_size,
                              hipStream_t stream) {
    const float* x = (const float*)d_in[0];   // (2,16,128,128) fp32
    const float* w = (const float*)d_in[1];   // (2,3328,128,128) fp32
    float* out = (float*)d_out;               // (2,16,128,128) fp32

    kan_kernel<<<dim3(2048), dim3(256), 0, stream>>>(x, w, out);
}

// Round 6
// 570.455 us; speedup vs baseline: 2.4911x; 2.4911x over previous
//
#include <hip/hip_runtime.h>

#define IN_C   16
#define OUT_C  16
#define COEF_M 11
#define PLANE  16384   // 128*128
#define WSIZE  3328    // IN_C*OUT_C*COEF_M + 2*IN_C*OUT_C
#define I0     2816    // IN_C*OUT_C*COEF_M
#define I1     3072    // I0 + IN_C*OUT_C

// v7: measured-recipe kernel = v1 granularity + v6 TLP.
//   thread = (1 pixel, 1 output channel), full i-sum in one scalar register.
//   block  = 256 contiguous px x 1 o  -> every wave-load is 64x4B = 256B
//            contiguous (v5 probe: zero line waste, FETCH 219MB).
//   grid   = 128 px-chunks x 16 o = 2048 blocks -> 8 blocks/CU, 32 waves/CU
//            (v6 counters: 90% occupancy sustains 3.4TB/s HBM).
//   No LDS, no barriers (v6 had 786K bank conflicts), no acc[] array.
//   w read exactly once (o-split disjoint); x re-read 16x (~32MB, L2).
//   Per i-iteration: 14 independent 256B wave-loads -> ~32 waves x 4-13 deep
//   x 256B = 32-100KB in flight per CU >= the ~32KB latency-hiding need.
__global__ __launch_bounds__(256) void kan_kernel(
    const float* __restrict__ x, const float* __restrict__ w,
    float* __restrict__ out)
{
    const int tid   = threadIdx.x;
    const int chunk = blockIdx.x & 127;   // px-chunk in low bits: concurrent
    const int o     = blockIdx.x >> 7;    // blocks sweep contiguous px
    const int pixel = chunk * 256 + tid;
    const int b     = pixel >> 14;        // chunks never straddle b
    const int hw    = pixel & (PLANE - 1);

    const float* wb = w + (size_t)b * WSIZE * PLANE + hw;
    const float* xb = x + (size_t)b * IN_C * PLANE + hw;

    const float* cbase = wb + (size_t)(o * COEF_M) * PLANE;  // + i*(OUT_C*COEF_M)*PLANE
    const float* ubase = wb + (size_t)(I0 + o) * PLANE;      // + i*OUT_C*PLANE
    const float* rbase = wb + (size_t)(I1 + o) * PLANE;

    float acc = 0.0f;

    for (int i = 0; i < IN_C; ++i) {
        const float xi = xb[(size_t)i * PLANE];

        // Cox-de Boor, order K=3, uniform knots t_j = -1.75 + 0.25*j
        float bp[14];
        #pragma unroll
        for (int j = 0; j < 14; ++j) {
            const float tj = -1.75f + 0.25f * j;
            bp[j] = (xi >= tj && xi < tj + 0.25f) ? 1.0f : 0.0f;
        }
        #pragma unroll
        for (int p = 1; p <= 3; ++p) {
            const float inv = 1.0f / (0.25f * (float)p);
            #pragma unroll
            for (int j = 0; j < 14 - p; ++j) {
                const float tj  = -1.75f + 0.25f * j;
                const float tp1 = tj + 0.25f * (float)(p + 1);
                bp[j] = (xi - tj) * inv * bp[j] + (tp1 - xi) * inv * bp[j + 1];
            }
        }

        const float sx = xi / (1.0f + __expf(-xi));   // silu

        const float* c = cbase + (size_t)(i * (OUT_C * COEF_M)) * PLANE;
        float sp = 0.0f;
        #pragma unroll
        for (int m = 0; m < COEF_M; ++m)
            sp += c[(size_t)m * PLANE] * bp[m];

        acc += ubase[(size_t)(i * OUT_C) * PLANE] * sp
             + rbase[(size_t)(i * OUT_C) * PLANE] * sx;
    }

    out[(size_t)b * (OUT_C * PLANE) + (size_t)o * PLANE + hw] = acc;
}

extern "C" void kernel_launch(void* const* d_in, const int* in_sizes, int n_in,
                              void* d_out, int out_size, void* d_ws, size_t ws_size,
                              hipStream_t stream) {
    const float* x = (const float*)d_in[0];   // (2,16,128,128) fp32
    const float* w = (const float*)d_in[1];   // (2,3328,128,128) fp32
    float* out = (float*)d_out;               // (2,16,128,128) fp32

    kan_kernel<<<dim3(2048), dim3(256), 0, stream>>>(x, w, out);
}